// Round 16
// baseline (813.388 us; speedup 1.0000x reference)
//
#include <hip/hip_runtime.h>
#include <hip/hip_bf16.h>
#include <cstdint>
#include <cstddef>

#define NAT 16384
#define NED 65536
#define BGR 256
#define FIN 64
#define HID 256
#define LPN 1024
#define HD 64

typedef __bf16 bf16x8 __attribute__((ext_vector_type(8)));
typedef float floatx4 __attribute__((ext_vector_type(4)));

// async global->LDS 16B; dest = wave-uniform base + lane*16 (linear layout!)
__device__ __forceinline__ void gl2lds16(const void* g, void* l)
{
    __builtin_amdgcn_global_load_lds(
        (const __attribute__((address_space(1))) unsigned int*)g,
        (__attribute__((address_space(3))) unsigned int*)l, 16, 0, 0);
}

// ---------------- bf16 MFMA GEMM, 8-wave, BK=64 double sub-buffer ------------
template<int ACT, int OUTBF16, int BIASROW>
__global__ __launch_bounds__(512) void gemm_mfma(const __bf16* __restrict__ A,
    const __bf16* __restrict__ Bt, const float* __restrict__ bias,
    void* __restrict__ Cout, int M, int Nn, int K, float escale)
{
    __shared__ __bf16 As[2][128][32];
    __shared__ __bf16 Bs[2][128][32];
    const int t = threadIdx.x;
    const int m0 = blockIdx.y * 128, n0 = blockIdx.x * 128;
    const int w = t >> 6, lane = t & 63;
    const int wm = (w & 3) * 32, wn = (w >> 2) * 64;
    const int quad = lane >> 4, l16 = lane & 15;
    const int r0 = t >> 2, s0 = t & 3, g0 = (s0 ^ (r0 & 3)) * 8;
    const int fso = (quad ^ (l16 & 3)) * 8;
    floatx4 acc[2][4] = {};
    for (int k0 = 0; k0 < K; k0 += 64) {
        gl2lds16(A + (size_t)(m0 + r0) * K + k0 + g0,       &As[0][r0][s0 * 8]);
        gl2lds16(A + (size_t)(m0 + r0) * K + k0 + 32 + g0,  &As[1][r0][s0 * 8]);
        gl2lds16(Bt + (size_t)(n0 + r0) * K + k0 + g0,      &Bs[0][r0][s0 * 8]);
        gl2lds16(Bt + (size_t)(n0 + r0) * K + k0 + 32 + g0, &Bs[1][r0][s0 * 8]);
        __syncthreads();
#pragma unroll
        for (int c = 0; c < 2; c++) {
            bf16x8 af[2], bfr[4];
#pragma unroll
            for (int mi = 0; mi < 2; mi++) af[mi]  = *(const bf16x8*)&As[c][wm + mi * 16 + l16][fso];
#pragma unroll
            for (int nj = 0; nj < 4; nj++) bfr[nj] = *(const bf16x8*)&Bs[c][wn + nj * 16 + l16][fso];
#pragma unroll
            for (int mi = 0; mi < 2; mi++)
#pragma unroll
                for (int nj = 0; nj < 4; nj++)
                    acc[mi][nj] = __builtin_amdgcn_mfma_f32_16x16x32_bf16(af[mi], bfr[nj], acc[mi][nj], 0, 0, 0);
        }
        __syncthreads();
    }
#pragma unroll
    for (int mi = 0; mi < 2; mi++)
#pragma unroll
        for (int nj = 0; nj < 4; nj++) {
            int col = n0 + wn + nj * 16 + l16;
#pragma unroll
            for (int r = 0; r < 4; r++) {
                int row = m0 + wm + mi * 16 + quad * 4 + r;
                float bval = bias ? (BIASROW ? bias[row] : bias[col]) : 0.f;
                float v = (acc[mi][nj][r] + bval) * escale;
                if (ACT == 1) v = fmaxf(v, 0.f);
                if (ACT == 2) v = 0.5f * v * (1.f + erff(v * 0.70710678118654752f));
                if (OUTBF16) ((__bf16*)Cout)[(size_t)row * Nn + col] = (__bf16)v;
                else         ((float*)Cout)[(size_t)row * Nn + col] = v;
            }
        }
}

// ------- fused conv + K-proj + V^T-proj: pconv computed from tap table -------
// grid (4, Mc/128): x = (z<<1)|yy, y = pconv-row tile.
// pconv side (z=0: A, z=1: B) computed in-register from tap; weight side async.
__global__ __launch_bounds__(512) void kvc_mfma(const int* __restrict__ seq,
    const float* __restrict__ tap, const float* __restrict__ conv_b,
    const __bf16* __restrict__ wkT, const __bf16* __restrict__ wvT,
    const float* __restrict__ bk, const float* __restrict__ bv,
    __bf16* __restrict__ kbb, __bf16* __restrict__ vtb, int Mc, int b0)
{
    __shared__ __bf16 As[2][128][32];
    __shared__ __bf16 Bs[2][128][32];
    const int t = threadIdx.x;
    const int z = blockIdx.x >> 1, yy = blockIdx.x & 1;
    const int tile = blockIdx.y;
    const int w = t >> 6, lane = t & 63;
    const int wm = (w & 3) * 32, wn = (w >> 2) * 64;
    const int quad = lane >> 4, l16 = lane & 15;
    const int r0 = t >> 2, s0 = t & 3, g0 = (s0 ^ (r0 & 3)) * 8;
    const int fso = (quad ^ (l16 & 3)) * 8;
    // pconv row for this thread (local to chunk)
    const int lrow = tile * 128 + r0;
    const int b = b0 + (lrow >> 10), l = lrow & 1023;
    const int* sr = seq + b * LPN;
    const int t0 = (l > 0) ? sr[l - 1] : -1;
    const int t1 = sr[l];
    const int t2 = (l < LPN - 1) ? sr[l + 1] : -1;
    const float* tp0 = (t0 >= 0) ? tap + (size_t)t0 * 256 : nullptr;
    const float* tp1 = tap + (size_t)(22 + t1) * 256;
    const float* tp2 = (t2 >= 0) ? tap + (size_t)(44 + t2) * 256 : nullptr;
    const __bf16* wT = z ? wvT : wkT;
    floatx4 acc[2][4] = {};
    for (int k0 = 0; k0 < 256; k0 += 64) {
        // weight side: async
        __bf16* Wb0 = z ? &As[0][r0][s0 * 8] : &Bs[0][r0][s0 * 8];
        __bf16* Wb1 = z ? &As[1][r0][s0 * 8] : &Bs[1][r0][s0 * 8];
        gl2lds16(wT + (size_t)(yy * 128 + r0) * 256 + k0 + g0,      Wb0);
        gl2lds16(wT + (size_t)(yy * 128 + r0) * 256 + k0 + 32 + g0, Wb1);
        // pconv side: compute 2 x 8 cols
#pragma unroll
        for (int c = 0; c < 2; c++) {
            const int col0 = k0 + c * 32 + g0;
            float v[8];
#pragma unroll
            for (int j = 0; j < 8; j++) v[j] = conv_b[col0 + j] + tp1[col0 + j];
            if (tp0) {
#pragma unroll
                for (int j = 0; j < 8; j++) v[j] += tp0[col0 + j];
            }
            if (tp2) {
#pragma unroll
                for (int j = 0; j < 8; j++) v[j] += tp2[col0 + j];
            }
            __bf16 o[8];
#pragma unroll
            for (int j = 0; j < 8; j++) o[j] = (__bf16)fmaxf(v[j], 0.f);
            __bf16* Pb = z ? &Bs[c][r0][s0 * 8] : &As[c][r0][s0 * 8];
            *(uint4*)Pb = *(uint4*)o;
        }
        __syncthreads();
#pragma unroll
        for (int c = 0; c < 2; c++) {
            bf16x8 af[2], bfr[4];
#pragma unroll
            for (int mi = 0; mi < 2; mi++) af[mi]  = *(const bf16x8*)&As[c][wm + mi * 16 + l16][fso];
#pragma unroll
            for (int nj = 0; nj < 4; nj++) bfr[nj] = *(const bf16x8*)&Bs[c][wn + nj * 16 + l16][fso];
#pragma unroll
            for (int mi = 0; mi < 2; mi++)
#pragma unroll
                for (int nj = 0; nj < 4; nj++)
                    acc[mi][nj] = __builtin_amdgcn_mfma_f32_16x16x32_bf16(af[mi], bfr[nj], acc[mi][nj], 0, 0, 0);
        }
        __syncthreads();
    }
    const int m0 = z ? yy * 128 : tile * 128;
    const int n0 = z ? tile * 128 : yy * 128;
    const int Nn = z ? Mc : 256;
    __bf16* out = z ? vtb : kbb;
#pragma unroll
    for (int mi = 0; mi < 2; mi++)
#pragma unroll
        for (int nj = 0; nj < 4; nj++) {
            int col = n0 + wn + nj * 16 + l16;
#pragma unroll
            for (int r = 0; r < 4; r++) {
                int row = m0 + wm + mi * 16 + quad * 4 + r;
                float bval = z ? bv[row] : bk[col];
                out[(size_t)row * Nn + col] = (__bf16)(acc[mi][nj][r] + bval);
            }
        }
}

// ---------------- GAT feature GEMM, BK=64: bf16 hg + partial a_s/a_d ---------
__global__ __launch_bounds__(512) void gemm_gat(const __bf16* __restrict__ A,
    const __bf16* __restrict__ Bt, const float* __restrict__ as_f,
    const float* __restrict__ ad_f, __bf16* __restrict__ Hg,
    float* __restrict__ part, int K)
{
    __shared__ __bf16 As[2][128][32];
    __shared__ __bf16 Bs[2][128][32];
    const int t = threadIdx.x;
    const int m0 = blockIdx.y * 128, n0 = blockIdx.x * 128;
    const int w = t >> 6, lane = t & 63;
    const int wm = (w & 3) * 32, wn = (w >> 2) * 64;
    const int quad = lane >> 4, l16 = lane & 15;
    const int r0 = t >> 2, s0 = t & 3, g0 = (s0 ^ (r0 & 3)) * 8;
    const int fso = (quad ^ (l16 & 3)) * 8;
    floatx4 acc[2][4] = {};
    for (int k0 = 0; k0 < K; k0 += 64) {
        gl2lds16(A + (size_t)(m0 + r0) * K + k0 + g0,       &As[0][r0][s0 * 8]);
        gl2lds16(A + (size_t)(m0 + r0) * K + k0 + 32 + g0,  &As[1][r0][s0 * 8]);
        gl2lds16(Bt + (size_t)(n0 + r0) * K + k0 + g0,      &Bs[0][r0][s0 * 8]);
        gl2lds16(Bt + (size_t)(n0 + r0) * K + k0 + 32 + g0, &Bs[1][r0][s0 * 8]);
        __syncthreads();
#pragma unroll
        for (int c = 0; c < 2; c++) {
            bf16x8 af[2], bfr[4];
#pragma unroll
            for (int mi = 0; mi < 2; mi++) af[mi]  = *(const bf16x8*)&As[c][wm + mi * 16 + l16][fso];
#pragma unroll
            for (int nj = 0; nj < 4; nj++) bfr[nj] = *(const bf16x8*)&Bs[c][wn + nj * 16 + l16][fso];
#pragma unroll
            for (int mi = 0; mi < 2; mi++)
#pragma unroll
                for (int nj = 0; nj < 4; nj++)
                    acc[mi][nj] = __builtin_amdgcn_mfma_f32_16x16x32_bf16(af[mi], bfr[nj], acc[mi][nj], 0, 0, 0);
        }
        __syncthreads();
    }
    const int slot = blockIdx.x * 2 + (w >> 2);
#pragma unroll
    for (int mi = 0; mi < 2; mi++) {
#pragma unroll
        for (int r = 0; r < 4; r++) {
            float ps = 0.f, pd = 0.f;
#pragma unroll
            for (int nj = 0; nj < 4; nj++) {
                int col = n0 + wn + nj * 16 + l16;
                float v = acc[mi][nj][r];
                ps += v * as_f[col];
                pd += v * ad_f[col];
            }
#pragma unroll
            for (int off = 1; off < 16; off <<= 1) {
                ps += __shfl_xor(ps, off, 64);
                pd += __shfl_xor(pd, off, 64);
            }
            if (l16 == 0) {
                int row = m0 + wm + mi * 16 + quad * 4 + r;
                part[(size_t)(slot * 2 + 0) * NAT + row] = ps;
                part[(size_t)(slot * 2 + 1) * NAT + row] = pd;
            }
        }
    }
#pragma unroll
    for (int mi = 0; mi < 2; mi++)
#pragma unroll
        for (int nj = 0; nj < 4; nj++) {
            int col = n0 + wn + nj * 16 + l16;
#pragma unroll
            for (int r = 0; r < 4; r++) {
                int row = m0 + wm + mi * 16 + quad * 4 + r;
                Hg[(size_t)row * 512 + col] = (__bf16)acc[mi][nj][r];
            }
        }
}

// fold 8 column-partials into a_s/a_d
__global__ void fold_k(const float* __restrict__ part, float* __restrict__ a_s,
                       float* __restrict__ a_d)
{
    int n = blockIdx.x * 256 + threadIdx.x;
    float s0 = 0.f, d0 = 0.f, s1 = 0.f, d1 = 0.f;
#pragma unroll
    for (int sl = 0; sl < 4; sl++) {
        s0 += part[(size_t)(sl * 2 + 0) * NAT + n];
        d0 += part[(size_t)(sl * 2 + 1) * NAT + n];
        s1 += part[(size_t)((sl + 4) * 2 + 0) * NAT + n];
        d1 += part[(size_t)((sl + 4) * 2 + 1) * NAT + n];
    }
    a_s[n * 2 + 0] = s0; a_s[n * 2 + 1] = s1;
    a_d[n * 2 + 0] = d0; a_d[n * 2 + 1] = d1;
}

// ---------------- conv tap table: tap[dl][v][n] = emb[v] . W[n, dl-tap] ------
__global__ __launch_bounds__(256) void tap_k(const float* __restrict__ emb,
    const float* __restrict__ cw, float* __restrict__ tap)
{
    const int dl = blockIdx.x / 22, v = blockIdx.x % 22;
    const int n = threadIdx.x;
    const float* er = emb + v * 256;
    const float* wr = cw + (size_t)n * 768 + dl;
    float s = 0.f;
    for (int k = 0; k < 256; k += 4) {
        s += er[k + 0] * wr[k * 3 + 0];
        s += er[k + 1] * wr[k * 3 + 3];
        s += er[k + 2] * wr[k * 3 + 6];
        s += er[k + 3] * wr[k * 3 + 9];
    }
    tap[(size_t)blockIdx.x * 256 + n] = s;
}

// ---------------- single fused conversion kernel ----------------
struct Segs {
    const float* src[12];
    __bf16* dst[12];
    int kdim[12];
    int ndim[12];
    int mode[12];          // 0 copy, 1 transpose
    int start[13];
};

__global__ void cvtall_k(Segs S, int total)
{
    int i = blockIdx.x * 256 + threadIdx.x;
    if (i >= total) return;
    int s = 0;
    while (i >= S.start[s + 1]) s++;
    int j = i - S.start[s];
    if (S.mode[s] == 0) {
        S.dst[s][j] = (__bf16)S.src[s][j];
    } else {
        int K = S.kdim[s], N = S.ndim[s];
        int n = j / K, k = j - n * K;
        S.dst[s][j] = (__bf16)S.src[s][(size_t)k * N + n];
    }
}

// ---------------- CSR build ----------------
__global__ void deg_k(const int* __restrict__ ei, int* __restrict__ deg)
{
    int e = blockIdx.x * 256 + threadIdx.x;
    if (e < NED) atomicAdd(&deg[ei[NED + e]], 1);
}

__global__ __launch_bounds__(256) void scan_k(const int* __restrict__ deg, int* __restrict__ rowptr)
{
    __shared__ int part[256];
    int t = threadIdx.x;
    int base = t * 64;
    int s = 0;
#pragma unroll
    for (int i = 0; i < 64; i++) s += deg[base + i];
    part[t] = s;
    __syncthreads();
    for (int off = 1; off < 256; off <<= 1) {
        int v = (t >= off) ? part[t - off] : 0;
        __syncthreads();
        part[t] += v;
        __syncthreads();
    }
    int run = t ? part[t - 1] : 0;
    for (int i = 0; i < 64; i++) { rowptr[base + i] = run; run += deg[base + i]; }
    if (t == 255) rowptr[16384] = run;
}

__global__ void scat_k(const int* __restrict__ ei, int* __restrict__ fill,
                       const int* __restrict__ rowptr, int* __restrict__ csrc,
                       int* __restrict__ cdst)
{
    int e = blockIdx.x * 256 + threadIdx.x;
    if (e >= NED) return;
    int d = ei[NED + e];
    int pos = rowptr[d] + atomicAdd(&fill[d], 1);
    csrc[pos] = ei[e];
    cdst[pos] = d;
}

// per-edge records in CSR order: {e0, e1, src-bits, 0}
__global__ void erec_k(const int* __restrict__ csrc, const int* __restrict__ cdst,
    const float* __restrict__ a_s, const float* __restrict__ a_d,
    float4* __restrict__ rec)
{
    int p = blockIdx.x * 256 + threadIdx.x;
    if (p >= NED) return;
    int s = csrc[p], d = cdst[p];
    float2 as2 = *(const float2*)(a_s + s * 2);
    float2 ad2 = *(const float2*)(a_d + d * 2);
    float e0 = as2.x + ad2.x; e0 = (e0 > 0.f) ? e0 : 0.2f * e0;
    float e1 = as2.y + ad2.y; e1 = (e1 > 0.f) ? e1 : 0.2f * e1;
    rec[p] = make_float4(e0, e1, __int_as_float(s), 0.f);
}

// ---------------- fused GAT aggregation over edge records ----------------
__global__ __launch_bounds__(256) void gat_agg(const int* __restrict__ rowptr,
    const float4* __restrict__ rec, const __bf16* __restrict__ hgb,
    const float* __restrict__ a_s, const float* __restrict__ a_d,
    const float* __restrict__ bias, float* __restrict__ out, __bf16* __restrict__ outb)
{
    const int wave = threadIdx.x >> 6, lane = threadIdx.x & 63;
    const int d = blockIdx.x * 4 + wave;
    const int beg = rowptr[d], end = rowptr[d + 1];
    float2 as2 = *(const float2*)(a_s + d * 2);
    float2 ad2 = *(const float2*)(a_d + d * 2);
    float e0 = as2.x + ad2.x; e0 = (e0 > 0.f) ? e0 : 0.2f * e0;
    float e1 = as2.y + ad2.y; e1 = (e1 > 0.f) ? e1 : 0.2f * e1;
    float m0 = e0, den0 = 1.f, m1 = e1, den1 = 1.f;
    for (int p = beg; p < end; p++) {
        float4 rc = rec[p];
        float nm0 = fmaxf(m0, rc.x);
        den0 = den0 * __expf(m0 - nm0) + __expf(rc.x - nm0);
        m0 = nm0;
        float nm1 = fmaxf(m1, rc.y);
        den1 = den1 * __expf(m1 - nm1) + __expf(rc.y - nm1);
        m1 = nm1;
    }
    const float inv0 = 1.f / den0, inv1 = 1.f / den1;
    const int ch = lane * 8;
    const int g = ch >> 8;
    const float mg = g ? m1 : m0, invg = g ? inv1 : inv0;
    float acc[8] = {};
    {
        float al = __expf((g ? e1 : e0) - mg) * invg;
        bf16x8 hv = *(const bf16x8*)(hgb + (size_t)d * 512 + ch);
#pragma unroll
        for (int j = 0; j < 8; j++) acc[j] += (float)hv[j] * al;
    }
    for (int p = beg; p < end; p++) {
        float4 rc = rec[p];
        float al = __expf((g ? rc.y : rc.x) - mg) * invg;
        int s = __float_as_int(rc.z);
        bf16x8 hv = *(const bf16x8*)(hgb + (size_t)s * 512 + ch);
#pragma unroll
        for (int j = 0; j < 8; j++) acc[j] += (float)hv[j] * al;
    }
    float other[8];
#pragma unroll
    for (int j = 0; j < 8; j++) other[j] = __shfl_xor(acc[j], 32, 64);
    if (lane < 32) {
#pragma unroll
        for (int j = 0; j < 8; j++) {
            float v = 0.5f * (acc[j] + other[j]) + bias[ch + j];
            v = (v > 0.f) ? v : expm1f(v);
            if (out) out[(size_t)d * 256 + ch + j] = v;
            outb[(size_t)d * 256 + ch + j] = (__bf16)v;
        }
    }
}

// ---------------- MFMA flash cross-attention, LP split x4 (bf16 partials) ----
__global__ __launch_bounds__(256) void attn3_k(const __bf16* __restrict__ Qb,
    const __bf16* __restrict__ Kb, const __bf16* __restrict__ Vtb,
    const int* __restrict__ seq, __bf16* __restrict__ Op, float* __restrict__ Ml,
    int b0, int ldV)
{
    __shared__ __bf16 Ps[4][16][72];
    __shared__ float mask_s[256];
    const int t = threadIdx.x;
    const int bl = blockIdx.x >> 4, h = (blockIdx.x >> 2) & 3, sp = blockIdx.x & 3;
    const int b = b0 + bl;
    const int w = t >> 6, lane = t & 63;
    const int quad = lane >> 4, l16 = lane & 15;
    if (t < 256)
        mask_s[t] = (seq[b * LPN + sp * 256 + t] == 0) ? -1e9f : 0.f;
    const __bf16* qrow = Qb + (size_t)(b * 64 + w * 16 + l16) * HID + h * HD;
    bf16x8 aq0 = *(const bf16x8*)(qrow + quad * 8);
    bf16x8 aq1 = *(const bf16x8*)(qrow + 32 + quad * 8);
    float m_run[4] = {-3e38f, -3e38f, -3e38f, -3e38f};
    float l_run[4] = {0.f, 0.f, 0.f, 0.f};
    floatx4 ctx[4] = {};
    __syncthreads();
    for (int kt = 0; kt < 4; kt++) {
        const int kp0 = sp * 256 + kt * 64;
        floatx4 s[4];
#pragma unroll
        for (int nj = 0; nj < 4; nj++) {
            const __bf16* krow = Kb + (size_t)(bl * LPN + kp0 + nj * 16 + l16) * HID + h * HD;
            bf16x8 bk0 = *(const bf16x8*)(krow + quad * 8);
            bf16x8 bk1 = *(const bf16x8*)(krow + 32 + quad * 8);
            floatx4 z = {0.f, 0.f, 0.f, 0.f};
            s[nj] = __builtin_amdgcn_mfma_f32_16x16x32_bf16(aq0, bk0, z, 0, 0, 0);
            s[nj] = __builtin_amdgcn_mfma_f32_16x16x32_bf16(aq1, bk1, s[nj], 0, 0, 0);
        }
#pragma unroll
        for (int nj = 0; nj < 4; nj++) {
            float mval = mask_s[kt * 64 + nj * 16 + l16];
#pragma unroll
            for (int r = 0; r < 4; r++) s[nj][r] += mval;
        }
        float alpha[4];
#pragma unroll
        for (int r = 0; r < 4; r++) {
            float mx = fmaxf(fmaxf(s[0][r], s[1][r]), fmaxf(s[2][r], s[3][r]));
#pragma unroll
            for (int off = 1; off < 16; off <<= 1) mx = fmaxf(mx, __shfl_xor(mx, off, 64));
            float mn = fmaxf(m_run[r], mx);
            alpha[r] = __expf(m_run[r] - mn);
            m_run[r] = mn;
            float rs = 0.f;
#pragma unroll
            for (int nj = 0; nj < 4; nj++) {
                float p = __expf(s[nj][r] - mn);
                s[nj][r] = p;
                rs += p;
            }
#pragma unroll
            for (int off = 1; off < 16; off <<= 1) rs += __shfl_xor(rs, off, 64);
            l_run[r] = l_run[r] * alpha[r] + rs;
        }
#pragma unroll
        for (int nj = 0; nj < 4; nj++)
#pragma unroll
            for (int r = 0; r < 4; r++)
                Ps[w][quad * 4 + r][nj * 16 + l16] = (__bf16)s[nj][r];
        bf16x8 pa0 = *(const bf16x8*)&Ps[w][l16][quad * 8];
        bf16x8 pa1 = *(const bf16x8*)&Ps[w][l16][32 + quad * 8];
#pragma unroll
        for (int dj = 0; dj < 4; dj++) {
#pragma unroll
            for (int r = 0; r < 4; r++) ctx[dj][r] *= alpha[r];
            const __bf16* vrow = Vtb + (size_t)(h * HD + dj * 16 + l16) * ldV + bl * LPN + kp0;
            bf16x8 bv0 = *(const bf16x8*)(vrow + quad * 8);
            bf16x8 bv1 = *(const bf16x8*)(vrow + 32 + quad * 8);
            ctx[dj] = __builtin_amdgcn_mfma_f32_16x16x32_bf16(pa0, bv0, ctx[dj], 0, 0, 0);
            ctx[dj] = __builtin_amdgcn_mfma_f32_16x16x32_bf16(pa1, bv1, ctx[dj], 0, 0, 0);
        }
    }
    const int base = ((bl * 4 + h) * 4 + sp) * 64;
#pragma unroll
    for (int dj = 0; dj < 4; dj++)
#pragma unroll
        for (int r = 0; r < 4; r++) {
            int q = w * 16 + quad * 4 + r;
            Op[(size_t)(base + q) * 64 + dj * 16 + l16] = (__bf16)(ctx[dj][r] / l_run[r]);
        }
    if (l16 == 0) {
#pragma unroll
        for (int r = 0; r < 4; r++) {
            int q = w * 16 + quad * 4 + r;
            Ml[(size_t)(base + q) * 2 + 0] = m_run[r];
            Ml[(size_t)(base + q) * 2 + 1] = l_run[r];
        }
    }
}

// combine 4 LP-split partials -> ctx bf16
__global__ __launch_bounds__(256) void combine_k(const __bf16* __restrict__ Op,
    const float* __restrict__ Ml, __bf16* __restrict__ O, int b0)
{
    const int bl = blockIdx.x >> 6, q = blockIdx.x & 63;
    const int t = threadIdx.x;
    const int h = t >> 6, d = t & 63;
    const int base = (bl * 4 + h) * 4;
    float ms[4], ls[4], m = -3e38f;
#pragma unroll
    for (int sp = 0; sp < 4; sp++) {
        ms[sp] = Ml[(size_t)((base + sp) * 64 + q) * 2 + 0];
        ls[sp] = Ml[(size_t)((base + sp) * 64 + q) * 2 + 1];
        m = fmaxf(m, ms[sp]);
    }
    float L = 0.f, o = 0.f;
#pragma unroll
    for (int sp = 0; sp < 4; sp++) {
        float wgt = __expf(ms[sp] - m) * ls[sp];
        L += wgt;
        o += wgt * (float)Op[(size_t)((base + sp) * 64 + q) * 64 + d];
    }
    O[((size_t)(b0 + bl) * 64 + q) * 256 + h * 64 + d] = (__bf16)(o / L);
}

// ---------------- LayerNorm(residual) ----------------
__device__ __forceinline__ float blockSum256(float v, float* red)
{
#pragma unroll
    for (int off = 32; off >= 1; off >>= 1) v += __shfl_down(v, off, 64);
    int wave = threadIdx.x >> 6, lane = threadIdx.x & 63;
    if (lane == 0) red[wave] = v;
    __syncthreads();
    float s = red[0] + red[1] + red[2] + red[3];
    __syncthreads();
    return s;
}

__global__ __launch_bounds__(256) void lnres_k(const float* __restrict__ A,
    const float* __restrict__ Bb, const float* __restrict__ g,
    const float* __restrict__ be, float* __restrict__ Y, __bf16* __restrict__ Yb)
{
    __shared__ float red[4];
    int r = blockIdx.x, t = threadIdx.x;
    float v = A[(size_t)r * 256 + t] + Bb[(size_t)r * 256 + t];
    float mean = blockSum256(v, red) * (1.f / 256.f);
    float d = v - mean;
    float var = blockSum256(d * d, red) * (1.f / 256.f);
    float o = d * rsqrtf(var + 1e-5f) * g[t] + be[t];
    Y[(size_t)r * 256 + t] = o;
    if (Yb) Yb[(size_t)r * 256 + t] = (__bf16)o;
}

// ---------------- fused head: mean-pool + fc1(relu) + fc2 ----------------
__global__ __launch_bounds__(256) void head_k(const float* __restrict__ Y,
    const float* __restrict__ fc1w, const float* __restrict__ fc1b,
    const float* __restrict__ fc2w, const float* __restrict__ fc2b,
    float* __restrict__ out)
{
    __shared__ float pooled[256];
    __shared__ float h[256];
    __shared__ float red[4];
    int b = blockIdx.x, t = threadIdx.x;
    float s = 0.f;
#pragma unroll 8
    for (int q = 0; q < 64; q++) s += Y[(size_t)(b * 64 + q) * 256 + t];
    pooled[t] = s / (64.f + 1e-6f);
    __syncthreads();
    float a = 0.f;
    for (int k = 0; k < 256; k += 4) {
        a += pooled[k + 0] * fc1w[(k + 0) * 256 + t];
        a += pooled[k + 1] * fc1w[(k + 1) * 256 + t];
        a += pooled[k + 2] * fc1w[(k + 2) * 256 + t];
        a += pooled[k + 3] * fc1w[(k + 3) * 256 + t];
    }
    h[t] = fmaxf(a + fc1b[t], 0.f);
    __syncthreads();
    float p = h[t] * fc2w[t];
    p = blockSum256(p, red);
    if (t == 0) out[b] = p + fc2b[0];
}

// ---------------- launch ----------------
extern "C" void kernel_launch(void* const* d_in, const int* in_sizes, int n_in,
                              void* d_out, int out_size, void* d_ws, size_t ws_size,
                              hipStream_t stream)
{
    const float* x     = (const float*)d_in[0];
    const int*   ei    = (const int*)d_in[1];
    const int*   pseq  = (const int*)d_in[3];
    const float* w1  = (const float*)d_in[4];
    const float* as1 = (const float*)d_in[5];
    const float* ad1 = (const float*)d_in[6];
    const float* b1  = (const float*)d_in[7];
    const float* w2  = (const float*)d_in[8];
    const float* as2 = (const float*)d_in[9];
    const float* ad2 = (const float*)d_in[10];
    const float* b2  = (const float*)d_in[11];
    const float* w3  = (const float*)d_in[12];
    const float* as3 = (const float*)d_in[13];
    const float* ad3 = (const float*)d_in[14];
    const float* b3  = (const float*)d_in[15];
    const float* emb    = (const float*)d_in[16];
    const float* conv_w = (const float*)d_in[17];
    const float* conv_b = (const float*)d_in[18];
    const float* wq = (const float*)d_in[19];
    const float* bq = (const float*)d_in[20];
    const float* wk = (const float*)d_in[21];
    const float* bk = (const float*)d_in[22];
    const float* wv = (const float*)d_in[23];
    const float* bv = (const float*)d_in[24];
    const float* wo = (const float*)d_in[25];
    const float* bo = (const float*)d_in[26];
    const float* ln1_g = (const float*)d_in[27];
    const float* ln1_b = (const float*)d_in[28];
    const float* ffw1  = (const float*)d_in[29];
    const float* ffb1  = (const float*)d_in[30];
    const float* ffw2  = (const float*)d_in[31];
    const float* ffb2  = (const float*)d_in[32];
    const float* ln2_g = (const float*)d_in[33];
    const float* ln2_b = (const float*)d_in[34];
    const float* fc1_w = (const float*)d_in[35];
    const float* fc1_b = (const float*)d_in[36];
    const float* fc2_w = (const float*)d_in[37];
    const float* fc2_b = (const float*)d_in[38];
    (void)in_sizes; (void)n_in; (void)out_size;

    char* ws = (char*)d_ws;
    size_t off = 0;
    auto alloc = [&](size_t bytes) -> char* {
        char* p = ws + off;
        off += (bytes + 255) & ~(size_t)255;
        return p;
    };
    // ---- fixed arena ----
    __bf16* hgb  = (__bf16*)alloc((size_t)NAT * 512 * 2);
    float* og    = (float*)alloc((size_t)NAT * 512 * 4);
    float* hb0   = (float*)alloc((size_t)NAT * 256 * 4);
    float* hb1   = (float*)alloc((size_t)NAT * 256 * 4);
    __bf16* xb   = (__bf16*)alloc((size_t)NAT * FIN * 2);
    __bf16* hbb  = (__bf16*)alloc((size_t)NAT * 256 * 2);
    __bf16* qbb  = (__bf16*)alloc((size_t)NAT * 256 * 2);
    __bf16* ctxbb= (__bf16*)alloc((size_t)NAT * 256 * 2);
    __bf16* ybb  = (__bf16*)alloc((size_t)NAT * 256 * 2);
    float* a_s   = (float*)alloc((size_t)NAT * 2 * 4);
    float* a_d   = (float*)alloc((size_t)NAT * 2 * 4);
    float* asd_p = (float*)alloc((size_t)16 * NAT * 4);
    int* deg     = (int*)alloc((size_t)NAT * 4);
    int* fill    = (int*)alloc((size_t)NAT * 4);
    int* rowptr  = (int*)alloc((size_t)(NAT + 1) * 4);
    int* csrc    = (int*)alloc((size_t)NED * 4);
    int* cdst    = (int*)alloc((size_t)NED * 4);
    float4* erec = (float4*)alloc((size_t)NED * 16);
    float* tap   = (float*)alloc((size_t)3 * 22 * 256 * 4);
    __bf16* w1T  = (__bf16*)alloc((size_t)512 * 64 * 2);
    __bf16* w2T  = (__bf16*)alloc((size_t)512 * 256 * 2);
    __bf16* w3T  = (__bf16*)alloc((size_t)512 * 256 * 2);
    __bf16* wkT  = (__bf16*)alloc((size_t)256 * 256 * 2);
    __bf16* wvT  = (__bf16*)alloc((size_t)256 * 256 * 2);
    __bf16* wqT  = (__bf16*)alloc((size_t)256 * 256 * 2);
    __bf16* woT  = (__bf16*)alloc((size_t)256 * 256 * 2);
    __bf16* f1T  = (__bf16*)alloc((size_t)1024 * 256 * 2);
    __bf16* f2T  = (__bf16*)alloc((size_t)256 * 1024 * 2);
    // ---- variable region ----
    size_t fixed_end = off;
    size_t rem = (ws_size > fixed_end) ? ws_size - fixed_end : 0;
    const size_t G1 = (size_t)LPN * 256 * 2;               // 0.5 MB: K or Vt per graph
    const size_t P1 = (size_t)4 * 4 * 64 * 64 * 2;         // 128 KB: bf16 partial O per graph
    const size_t M1 = (size_t)4 * 4 * 64 * 2 * 4;          // 8 KB: m,l per graph
    const size_t ffneed = (size_t)NAT * 1024 * 2 + (size_t)NAT * 256 * 4;
    int CB = 8;
    {
        const int cands[6] = {256, 128, 64, 32, 16, 8};
        for (int ci = 0; ci < 6; ci++) {
            size_t regneed = (size_t)cands[ci] * (2 * G1 + P1 + M1);
            if (regneed < ffneed) regneed = ffneed;
            if (regneed <= rem) { CB = cands[ci]; break; }
        }
    }
    char* region   = ws + fixed_end;
    __bf16* kbb    = (__bf16*)region;
    __bf16* vtb    = (__bf16*)(region + (size_t)CB * G1);
    __bf16* opart  = (__bf16*)(region + 2 * (size_t)CB * G1);
    float*  mlpart = (float*)(region + (size_t)CB * (2 * G1 + P1));
    __bf16* ffbb   = (__bf16*)region;
    float*  y2     = (float*)(region + (size_t)NAT * 1024 * 2);
    float* attno = og;
    float* ybuf  = og + (size_t)NAT * 256;
    float* ff2o  = hb1;

    // ---------------- CSR build + conv tap table ----------------
    hipMemsetAsync(deg, 0, (size_t)NAT * 8, stream);   // deg + fill (adjacent)
    deg_k<<<NED / 256, 256, 0, stream>>>(ei, deg);
    scan_k<<<1, 256, 0, stream>>>(deg, rowptr);
    scat_k<<<NED / 256, 256, 0, stream>>>(ei, fill, rowptr, csrc, cdst);
    tap_k<<<66, 256, 0, stream>>>(emb, conv_w, tap);

    // ---------------- all conversions in one dispatch ----------------
    {
        Segs S;
        const float* srcs[10] = {x, w1, w2, w3, wk, wv, wq, wo, ffw1, ffw2};
        __bf16* dsts[10] = {xb, w1T, w2T, w3T, wkT, wvT, wqT, woT, f1T, f2T};
        int kd[10] = {0, 64, 256, 256, 256, 256, 256, 256, 256, 1024};
        int nd[10] = {0, 512, 512, 512, 256, 256, 256, 256, 1024, 256};
        int md[10] = {0, 1, 1, 1, 1, 1, 1, 1, 1, 1};
        int cnt[10] = {NAT * FIN, 32768, 131072, 131072,
                       65536, 65536, 65536, 65536, 262144, 262144};
        int run = 0;
        for (int i = 0; i < 10; i++) {
            S.src[i] = srcs[i]; S.dst[i] = dsts[i];
            S.kdim[i] = kd[i]; S.ndim[i] = nd[i]; S.mode[i] = md[i];
            S.start[i] = run; run += cnt[i];
        }
        S.start[10] = run; S.start[11] = run; S.start[12] = run;
        cvtall_k<<<(run + 255) / 256, 256, 0, stream>>>(S, run);
    }

    // ---------------- ligand GNN: 3 GAT layers ----------------
    const __bf16* WT[3] = {w1T, w2T, w3T};
    const float* asl[3] = {as1, as2, as3};
    const float* adl[3] = {ad1, ad2, ad3};
    const float* bl[3]  = {b1, b2, b3};
    float* houts[3] = {nullptr, nullptr, hb0};
    const __bf16* hinb = xb;
    int Kdim = FIN;
    for (int l = 0; l < 3; l++) {
        gemm_gat<<<dim3(4, NAT / 128), 512, 0, stream>>>(hinb, WT[l], asl[l], adl[l], hgb, asd_p, Kdim);
        fold_k<<<NAT / 256, 256, 0, stream>>>(asd_p, a_s, a_d);
        erec_k<<<NED / 256, 256, 0, stream>>>(csrc, cdst, a_s, a_d, erec);
        gat_agg<<<NAT / 4, 256, 0, stream>>>(rowptr, erec, hgb, a_s, a_d, bl[l], houts[l], hbb);
        hinb = hbb;
        Kdim = HID;
    }
    const float* lig = hb0;
    const __bf16* ligb = hbb;

    // ---------------- Q projection (scale 1/8 folded in) ----------------
    gemm_mfma<0, 1, 0><<<dim3(2, NAT / 128), 512, 0, stream>>>(ligb, wqT, bq, qbb, NAT, 256, 256, 0.125f);

    // ---------------- protein branch + attention, chunked over graphs ----------
    for (int b0 = 0; b0 < BGR; b0 += CB) {
        int Mc = CB * LPN;
        kvc_mfma<<<dim3(4, Mc / 128), 512, 0, stream>>>(pseq, tap, conv_b, wkT, wvT, bk, bv, kbb, vtb, Mc, b0);
        attn3_k<<<CB * 16, 256, 0, stream>>>(qbb, kbb, vtb, pseq, opart, mlpart, b0, Mc);
        combine_k<<<CB * 64, 256, 0, stream>>>(opart, mlpart, ctxbb, b0);
    }

    // ---------------- attention out proj + LN + FFN + LN ----------------
    gemm_mfma<0, 0, 0><<<dim3(2, NAT / 128), 512, 0, stream>>>(ctxbb, woT, bo, attno, NAT, 256, 256, 1.f);
    lnres_k<<<NAT, 256, 0, stream>>>(lig, attno, ln1_g, ln1_b, ybuf, ybb);
    gemm_mfma<2, 1, 0><<<dim3(8, NAT / 128), 512, 0, stream>>>(ybb, f1T, ffb1, ffbb, NAT, 1024, 256, 1.f);
    gemm_mfma<0, 0, 0><<<dim3(2, NAT / 128), 512, 0, stream>>>(ffbb, f2T, ffb2, ff2o, NAT, 256, 1024, 1.f);
    lnres_k<<<NAT, 256, 0, stream>>>(ybuf, ff2o, ln2_g, ln2_b, y2, nullptr);

    // ---------------- fused head ----------------
    head_k<<<BGR, 256, 0, stream>>>(y2, fc1_w, fc1_b, fc2_w, fc2_b, (float*)d_out);
}

// Round 17
// 792.632 us; speedup vs baseline: 1.0262x; 1.0262x over previous
//
#include <hip/hip_runtime.h>
#include <hip/hip_bf16.h>
#include <cstdint>
#include <cstddef>

#define NAT 16384
#define NED 65536
#define BGR 256
#define FIN 64
#define HID 256
#define LPN 1024
#define HD 64

typedef __bf16 bf16x8 __attribute__((ext_vector_type(8)));
typedef float floatx4 __attribute__((ext_vector_type(4)));

// async global->LDS 16B; dest = wave-uniform base + lane*16 (linear layout!)
__device__ __forceinline__ void gl2lds16(const void* g, void* l)
{
    __builtin_amdgcn_global_load_lds(
        (const __attribute__((address_space(1))) unsigned int*)g,
        (__attribute__((address_space(3))) unsigned int*)l, 16, 0, 0);
}

// ---------------- bf16 MFMA GEMM, 8-wave, BK=64 double sub-buffer ------------
template<int ACT, int OUTBF16, int BIASROW>
__global__ __launch_bounds__(512) void gemm_mfma(const __bf16* __restrict__ A,
    const __bf16* __restrict__ Bt, const float* __restrict__ bias,
    void* __restrict__ Cout, int M, int Nn, int K, float escale)
{
    __shared__ __bf16 As[2][128][32];
    __shared__ __bf16 Bs[2][128][32];
    const int t = threadIdx.x;
    const int m0 = blockIdx.y * 128, n0 = blockIdx.x * 128;
    const int w = t >> 6, lane = t & 63;
    const int wm = (w & 3) * 32, wn = (w >> 2) * 64;
    const int quad = lane >> 4, l16 = lane & 15;
    const int r0 = t >> 2, s0 = t & 3, g0 = (s0 ^ (r0 & 3)) * 8;
    const int fso = (quad ^ (l16 & 3)) * 8;
    floatx4 acc[2][4] = {};
    for (int k0 = 0; k0 < K; k0 += 64) {
        gl2lds16(A + (size_t)(m0 + r0) * K + k0 + g0,       &As[0][r0][s0 * 8]);
        gl2lds16(A + (size_t)(m0 + r0) * K + k0 + 32 + g0,  &As[1][r0][s0 * 8]);
        gl2lds16(Bt + (size_t)(n0 + r0) * K + k0 + g0,      &Bs[0][r0][s0 * 8]);
        gl2lds16(Bt + (size_t)(n0 + r0) * K + k0 + 32 + g0, &Bs[1][r0][s0 * 8]);
        __syncthreads();
#pragma unroll
        for (int c = 0; c < 2; c++) {
            bf16x8 af[2], bfr[4];
#pragma unroll
            for (int mi = 0; mi < 2; mi++) af[mi]  = *(const bf16x8*)&As[c][wm + mi * 16 + l16][fso];
#pragma unroll
            for (int nj = 0; nj < 4; nj++) bfr[nj] = *(const bf16x8*)&Bs[c][wn + nj * 16 + l16][fso];
#pragma unroll
            for (int mi = 0; mi < 2; mi++)
#pragma unroll
                for (int nj = 0; nj < 4; nj++)
                    acc[mi][nj] = __builtin_amdgcn_mfma_f32_16x16x32_bf16(af[mi], bfr[nj], acc[mi][nj], 0, 0, 0);
        }
        __syncthreads();
    }
#pragma unroll
    for (int mi = 0; mi < 2; mi++)
#pragma unroll
        for (int nj = 0; nj < 4; nj++) {
            int col = n0 + wn + nj * 16 + l16;
#pragma unroll
            for (int r = 0; r < 4; r++) {
                int row = m0 + wm + mi * 16 + quad * 4 + r;
                float bval = bias ? (BIASROW ? bias[row] : bias[col]) : 0.f;
                float v = (acc[mi][nj][r] + bval) * escale;
                if (ACT == 1) v = fmaxf(v, 0.f);
                if (ACT == 2) v = 0.5f * v * (1.f + erff(v * 0.70710678118654752f));
                if (OUTBF16) ((__bf16*)Cout)[(size_t)row * Nn + col] = (__bf16)v;
                else         ((float*)Cout)[(size_t)row * Nn + col] = v;
            }
        }
}

// ---------------- merged K-proj + V^T-proj, BK=64 ----------------------------
__global__ __launch_bounds__(512) void kv_mfma(const __bf16* __restrict__ pconv,
    const __bf16* __restrict__ wkT, const __bf16* __restrict__ wvT,
    const float* __restrict__ bk, const float* __restrict__ bv,
    __bf16* __restrict__ kbb, __bf16* __restrict__ vtb, int Mc)
{
    __shared__ __bf16 As[2][128][32];
    __shared__ __bf16 Bs[2][128][32];
    const int t = threadIdx.x;
    const int z = blockIdx.x >> 1, yy = blockIdx.x & 1;
    const int tile = blockIdx.y;
    const int m0 = z ? yy * 128 : tile * 128;
    const int n0 = z ? tile * 128 : yy * 128;
    const __bf16* A  = z ? wvT   : pconv;
    const __bf16* Bt = z ? pconv : wkT;
    const int Nn = z ? Mc : 256;
    const int w = t >> 6, lane = t & 63;
    const int wm = (w & 3) * 32, wn = (w >> 2) * 64;
    const int quad = lane >> 4, l16 = lane & 15;
    const int r0 = t >> 2, s0 = t & 3, g0 = (s0 ^ (r0 & 3)) * 8;
    const int fso = (quad ^ (l16 & 3)) * 8;
    floatx4 acc[2][4] = {};
    for (int k0 = 0; k0 < 256; k0 += 64) {
        gl2lds16(A + (size_t)(m0 + r0) * 256 + k0 + g0,       &As[0][r0][s0 * 8]);
        gl2lds16(A + (size_t)(m0 + r0) * 256 + k0 + 32 + g0,  &As[1][r0][s0 * 8]);
        gl2lds16(Bt + (size_t)(n0 + r0) * 256 + k0 + g0,      &Bs[0][r0][s0 * 8]);
        gl2lds16(Bt + (size_t)(n0 + r0) * 256 + k0 + 32 + g0, &Bs[1][r0][s0 * 8]);
        __syncthreads();
#pragma unroll
        for (int c = 0; c < 2; c++) {
            bf16x8 af[2], bfr[4];
#pragma unroll
            for (int mi = 0; mi < 2; mi++) af[mi]  = *(const bf16x8*)&As[c][wm + mi * 16 + l16][fso];
#pragma unroll
            for (int nj = 0; nj < 4; nj++) bfr[nj] = *(const bf16x8*)&Bs[c][wn + nj * 16 + l16][fso];
#pragma unroll
            for (int mi = 0; mi < 2; mi++)
#pragma unroll
                for (int nj = 0; nj < 4; nj++)
                    acc[mi][nj] = __builtin_amdgcn_mfma_f32_16x16x32_bf16(af[mi], bfr[nj], acc[mi][nj], 0, 0, 0);
        }
        __syncthreads();
    }
    __bf16* out = z ? vtb : kbb;
#pragma unroll
    for (int mi = 0; mi < 2; mi++)
#pragma unroll
        for (int nj = 0; nj < 4; nj++) {
            int col = n0 + wn + nj * 16 + l16;
#pragma unroll
            for (int r = 0; r < 4; r++) {
                int row = m0 + wm + mi * 16 + quad * 4 + r;
                float bval = z ? bv[row] : bk[col];
                out[(size_t)row * Nn + col] = (__bf16)(acc[mi][nj][r] + bval);
            }
        }
}

// ---------------- GAT feature GEMM, BK=64: bf16 hg + partial a_s/a_d ---------
__global__ __launch_bounds__(512) void gemm_gat(const __bf16* __restrict__ A,
    const __bf16* __restrict__ Bt, const float* __restrict__ as_f,
    const float* __restrict__ ad_f, __bf16* __restrict__ Hg,
    float* __restrict__ part, int K)
{
    __shared__ __bf16 As[2][128][32];
    __shared__ __bf16 Bs[2][128][32];
    const int t = threadIdx.x;
    const int m0 = blockIdx.y * 128, n0 = blockIdx.x * 128;
    const int w = t >> 6, lane = t & 63;
    const int wm = (w & 3) * 32, wn = (w >> 2) * 64;
    const int quad = lane >> 4, l16 = lane & 15;
    const int r0 = t >> 2, s0 = t & 3, g0 = (s0 ^ (r0 & 3)) * 8;
    const int fso = (quad ^ (l16 & 3)) * 8;
    floatx4 acc[2][4] = {};
    for (int k0 = 0; k0 < K; k0 += 64) {
        gl2lds16(A + (size_t)(m0 + r0) * K + k0 + g0,       &As[0][r0][s0 * 8]);
        gl2lds16(A + (size_t)(m0 + r0) * K + k0 + 32 + g0,  &As[1][r0][s0 * 8]);
        gl2lds16(Bt + (size_t)(n0 + r0) * K + k0 + g0,      &Bs[0][r0][s0 * 8]);
        gl2lds16(Bt + (size_t)(n0 + r0) * K + k0 + 32 + g0, &Bs[1][r0][s0 * 8]);
        __syncthreads();
#pragma unroll
        for (int c = 0; c < 2; c++) {
            bf16x8 af[2], bfr[4];
#pragma unroll
            for (int mi = 0; mi < 2; mi++) af[mi]  = *(const bf16x8*)&As[c][wm + mi * 16 + l16][fso];
#pragma unroll
            for (int nj = 0; nj < 4; nj++) bfr[nj] = *(const bf16x8*)&Bs[c][wn + nj * 16 + l16][fso];
#pragma unroll
            for (int mi = 0; mi < 2; mi++)
#pragma unroll
                for (int nj = 0; nj < 4; nj++)
                    acc[mi][nj] = __builtin_amdgcn_mfma_f32_16x16x32_bf16(af[mi], bfr[nj], acc[mi][nj], 0, 0, 0);
        }
        __syncthreads();
    }
    const int slot = blockIdx.x * 2 + (w >> 2);
#pragma unroll
    for (int mi = 0; mi < 2; mi++) {
#pragma unroll
        for (int r = 0; r < 4; r++) {
            float ps = 0.f, pd = 0.f;
#pragma unroll
            for (int nj = 0; nj < 4; nj++) {
                int col = n0 + wn + nj * 16 + l16;
                float v = acc[mi][nj][r];
                ps += v * as_f[col];
                pd += v * ad_f[col];
            }
#pragma unroll
            for (int off = 1; off < 16; off <<= 1) {
                ps += __shfl_xor(ps, off, 64);
                pd += __shfl_xor(pd, off, 64);
            }
            if (l16 == 0) {
                int row = m0 + wm + mi * 16 + quad * 4 + r;
                part[(size_t)(slot * 2 + 0) * NAT + row] = ps;
                part[(size_t)(slot * 2 + 1) * NAT + row] = pd;
            }
        }
    }
#pragma unroll
    for (int mi = 0; mi < 2; mi++)
#pragma unroll
        for (int nj = 0; nj < 4; nj++) {
            int col = n0 + wn + nj * 16 + l16;
#pragma unroll
            for (int r = 0; r < 4; r++) {
                int row = m0 + wm + mi * 16 + quad * 4 + r;
                Hg[(size_t)row * 512 + col] = (__bf16)acc[mi][nj][r];
            }
        }
}

// fold 8 column-partials into a_s/a_d
__global__ void fold_k(const float* __restrict__ part, float* __restrict__ a_s,
                       float* __restrict__ a_d)
{
    int n = blockIdx.x * 256 + threadIdx.x;
    float s0 = 0.f, d0 = 0.f, s1 = 0.f, d1 = 0.f;
#pragma unroll
    for (int sl = 0; sl < 4; sl++) {
        s0 += part[(size_t)(sl * 2 + 0) * NAT + n];
        d0 += part[(size_t)(sl * 2 + 1) * NAT + n];
        s1 += part[(size_t)((sl + 4) * 2 + 0) * NAT + n];
        d1 += part[(size_t)((sl + 4) * 2 + 1) * NAT + n];
    }
    a_s[n * 2 + 0] = s0; a_s[n * 2 + 1] = s1;
    a_d[n * 2 + 0] = d0; a_d[n * 2 + 1] = d1;
}

// ---------------- conv tap table, 4-way k-split: tap[dl][v][n] += partial ----
__global__ __launch_bounds__(256) void tap_k(const float* __restrict__ emb,
    const float* __restrict__ cw, float* __restrict__ tap)
{
    const int dlv = blockIdx.x >> 2, part = blockIdx.x & 3;
    const int dl = dlv / 22, v = dlv % 22;
    const int n = threadIdx.x;
    const float* er = emb + v * 256 + part * 64;
    const float* wr = cw + (size_t)n * 768 + part * 192 + dl;
    float s = 0.f;
    for (int k = 0; k < 64; k += 4) {
        s += er[k + 0] * wr[k * 3 + 0];
        s += er[k + 1] * wr[k * 3 + 3];
        s += er[k + 2] * wr[k * 3 + 6];
        s += er[k + 3] * wr[k * 3 + 9];
    }
    atomicAdd(&tap[(size_t)dlv * 256 + n], s);
}

// ---------------- conv1d as gather-add over the 22-token tap table -----------
// pconv[lrow][n] = relu(tap[0][seq[l-1]] + tap[1][seq[l]] + tap[2][seq[l+1]] + bias)
__global__ __launch_bounds__(256) void convg_k(const int* __restrict__ seq,
    const float* __restrict__ tap, const float* __restrict__ bias,
    __bf16* __restrict__ C, int b_base)
{
    const int t = threadIdx.x;
    const int lrow = blockIdx.x * 8 + (t >> 5);
    const int c = (t & 31) * 8;
    const int b = b_base + (lrow >> 10), l = lrow & 1023;
    const int* sr = seq + b * LPN;
    int t0 = (l > 0) ? sr[l - 1] : -1;
    int t1 = sr[l];
    int t2 = (l < LPN - 1) ? sr[l + 1] : -1;
    float acc[8];
#pragma unroll
    for (int j = 0; j < 8; j++) acc[j] = bias[c + j];
    if (t0 >= 0) {
        const float* r = tap + (size_t)(0 * 22 + t0) * 256 + c;
#pragma unroll
        for (int j = 0; j < 8; j++) acc[j] += r[j];
    }
    {
        const float* r = tap + (size_t)(1 * 22 + t1) * 256 + c;
#pragma unroll
        for (int j = 0; j < 8; j++) acc[j] += r[j];
    }
    if (t2 >= 0) {
        const float* r = tap + (size_t)(2 * 22 + t2) * 256 + c;
#pragma unroll
        for (int j = 0; j < 8; j++) acc[j] += r[j];
    }
    __bf16 o[8];
#pragma unroll
    for (int j = 0; j < 8; j++) o[j] = (__bf16)fmaxf(acc[j], 0.f);
    *(uint4*)(C + (size_t)lrow * 256 + c) = *(uint4*)o;
}

// ---------------- single fused conversion kernel ----------------
struct Segs {
    const float* src[12];
    __bf16* dst[12];
    int kdim[12];
    int ndim[12];
    int mode[12];          // 0 copy, 1 transpose
    int start[13];
};

__global__ void cvtall_k(Segs S, int total)
{
    int i = blockIdx.x * 256 + threadIdx.x;
    if (i >= total) return;
    int s = 0;
    while (i >= S.start[s + 1]) s++;
    int j = i - S.start[s];
    if (S.mode[s] == 0) {
        S.dst[s][j] = (__bf16)S.src[s][j];
    } else {
        int K = S.kdim[s], N = S.ndim[s];
        int n = j / K, k = j - n * K;
        S.dst[s][j] = (__bf16)S.src[s][(size_t)k * N + n];
    }
}

// ---------------- CSR build ----------------
__global__ void deg_k(const int* __restrict__ ei, int* __restrict__ deg)
{
    int e = blockIdx.x * 256 + threadIdx.x;
    if (e < NED) atomicAdd(&deg[ei[NED + e]], 1);
}

__global__ __launch_bounds__(256) void scan_k(const int* __restrict__ deg, int* __restrict__ rowptr)
{
    __shared__ int part[256];
    int t = threadIdx.x;
    int base = t * 64;
    int s = 0;
#pragma unroll
    for (int i = 0; i < 64; i++) s += deg[base + i];
    part[t] = s;
    __syncthreads();
    for (int off = 1; off < 256; off <<= 1) {
        int v = (t >= off) ? part[t - off] : 0;
        __syncthreads();
        part[t] += v;
        __syncthreads();
    }
    int run = t ? part[t - 1] : 0;
    for (int i = 0; i < 64; i++) { rowptr[base + i] = run; run += deg[base + i]; }
    if (t == 255) rowptr[16384] = run;
}

__global__ void scat_k(const int* __restrict__ ei, int* __restrict__ fill,
                       const int* __restrict__ rowptr, int* __restrict__ csrc,
                       int* __restrict__ cdst)
{
    int e = blockIdx.x * 256 + threadIdx.x;
    if (e >= NED) return;
    int d = ei[NED + e];
    int pos = rowptr[d] + atomicAdd(&fill[d], 1);
    csrc[pos] = ei[e];
    cdst[pos] = d;
}

// per-edge records in CSR order: {e0, e1, src-bits, 0}
__global__ void erec_k(const int* __restrict__ csrc, const int* __restrict__ cdst,
    const float* __restrict__ a_s, const float* __restrict__ a_d,
    float4* __restrict__ rec)
{
    int p = blockIdx.x * 256 + threadIdx.x;
    if (p >= NED) return;
    int s = csrc[p], d = cdst[p];
    float2 as2 = *(const float2*)(a_s + s * 2);
    float2 ad2 = *(const float2*)(a_d + d * 2);
    float e0 = as2.x + ad2.x; e0 = (e0 > 0.f) ? e0 : 0.2f * e0;
    float e1 = as2.y + ad2.y; e1 = (e1 > 0.f) ? e1 : 0.2f * e1;
    rec[p] = make_float4(e0, e1, __int_as_float(s), 0.f);
}

// ---------------- fused GAT aggregation over edge records ----------------
__global__ __launch_bounds__(256) void gat_agg(const int* __restrict__ rowptr,
    const float4* __restrict__ rec, const __bf16* __restrict__ hgb,
    const float* __restrict__ a_s, const float* __restrict__ a_d,
    const float* __restrict__ bias, float* __restrict__ out, __bf16* __restrict__ outb)
{
    const int wave = threadIdx.x >> 6, lane = threadIdx.x & 63;
    const int d = blockIdx.x * 4 + wave;
    const int beg = rowptr[d], end = rowptr[d + 1];
    float2 as2 = *(const float2*)(a_s + d * 2);
    float2 ad2 = *(const float2*)(a_d + d * 2);
    float e0 = as2.x + ad2.x; e0 = (e0 > 0.f) ? e0 : 0.2f * e0;
    float e1 = as2.y + ad2.y; e1 = (e1 > 0.f) ? e1 : 0.2f * e1;
    float m0 = e0, den0 = 1.f, m1 = e1, den1 = 1.f;
    for (int p = beg; p < end; p++) {
        float4 rc = rec[p];
        float nm0 = fmaxf(m0, rc.x);
        den0 = den0 * __expf(m0 - nm0) + __expf(rc.x - nm0);
        m0 = nm0;
        float nm1 = fmaxf(m1, rc.y);
        den1 = den1 * __expf(m1 - nm1) + __expf(rc.y - nm1);
        m1 = nm1;
    }
    const float inv0 = 1.f / den0, inv1 = 1.f / den1;
    const int ch = lane * 8;
    const int g = ch >> 8;
    const float mg = g ? m1 : m0, invg = g ? inv1 : inv0;
    float acc[8] = {};
    {
        float al = __expf((g ? e1 : e0) - mg) * invg;
        bf16x8 hv = *(const bf16x8*)(hgb + (size_t)d * 512 + ch);
#pragma unroll
        for (int j = 0; j < 8; j++) acc[j] += (float)hv[j] * al;
    }
    for (int p = beg; p < end; p++) {
        float4 rc = rec[p];
        float al = __expf((g ? rc.y : rc.x) - mg) * invg;
        int s = __float_as_int(rc.z);
        bf16x8 hv = *(const bf16x8*)(hgb + (size_t)s * 512 + ch);
#pragma unroll
        for (int j = 0; j < 8; j++) acc[j] += (float)hv[j] * al;
    }
    float other[8];
#pragma unroll
    for (int j = 0; j < 8; j++) other[j] = __shfl_xor(acc[j], 32, 64);
    if (lane < 32) {
#pragma unroll
        for (int j = 0; j < 8; j++) {
            float v = 0.5f * (acc[j] + other[j]) + bias[ch + j];
            v = (v > 0.f) ? v : expm1f(v);
            if (out) out[(size_t)d * 256 + ch + j] = v;
            outb[(size_t)d * 256 + ch + j] = (__bf16)v;
        }
    }
}

// ---------------- MFMA flash cross-attention, LP split x4 (bf16 partials) ----
__global__ __launch_bounds__(256) void attn3_k(const __bf16* __restrict__ Qb,
    const __bf16* __restrict__ Kb, const __bf16* __restrict__ Vtb,
    const int* __restrict__ seq, __bf16* __restrict__ Op, float* __restrict__ Ml,
    int b0, int ldV)
{
    __shared__ __bf16 Ps[4][16][72];
    __shared__ float mask_s[256];
    const int t = threadIdx.x;
    const int bl = blockIdx.x >> 4, h = (blockIdx.x >> 2) & 3, sp = blockIdx.x & 3;
    const int b = b0 + bl;
    const int w = t >> 6, lane = t & 63;
    const int quad = lane >> 4, l16 = lane & 15;
    if (t < 256)
        mask_s[t] = (seq[b * LPN + sp * 256 + t] == 0) ? -1e9f : 0.f;
    const __bf16* qrow = Qb + (size_t)(b * 64 + w * 16 + l16) * HID + h * HD;
    bf16x8 aq0 = *(const bf16x8*)(qrow + quad * 8);
    bf16x8 aq1 = *(const bf16x8*)(qrow + 32 + quad * 8);
    float m_run[4] = {-3e38f, -3e38f, -3e38f, -3e38f};
    float l_run[4] = {0.f, 0.f, 0.f, 0.f};
    floatx4 ctx[4] = {};
    __syncthreads();
    for (int kt = 0; kt < 4; kt++) {
        const int kp0 = sp * 256 + kt * 64;
        floatx4 s[4];
#pragma unroll
        for (int nj = 0; nj < 4; nj++) {
            const __bf16* krow = Kb + (size_t)(bl * LPN + kp0 + nj * 16 + l16) * HID + h * HD;
            bf16x8 bk0 = *(const bf16x8*)(krow + quad * 8);
            bf16x8 bk1 = *(const bf16x8*)(krow + 32 + quad * 8);
            floatx4 z = {0.f, 0.f, 0.f, 0.f};
            s[nj] = __builtin_amdgcn_mfma_f32_16x16x32_bf16(aq0, bk0, z, 0, 0, 0);
            s[nj] = __builtin_amdgcn_mfma_f32_16x16x32_bf16(aq1, bk1, s[nj], 0, 0, 0);
        }
#pragma unroll
        for (int nj = 0; nj < 4; nj++) {
            float mval = mask_s[kt * 64 + nj * 16 + l16];
#pragma unroll
            for (int r = 0; r < 4; r++) s[nj][r] += mval;
        }
        float alpha[4];
#pragma unroll
        for (int r = 0; r < 4; r++) {
            float mx = fmaxf(fmaxf(s[0][r], s[1][r]), fmaxf(s[2][r], s[3][r]));
#pragma unroll
            for (int off = 1; off < 16; off <<= 1) mx = fmaxf(mx, __shfl_xor(mx, off, 64));
            float mn = fmaxf(m_run[r], mx);
            alpha[r] = __expf(m_run[r] - mn);
            m_run[r] = mn;
            float rs = 0.f;
#pragma unroll
            for (int nj = 0; nj < 4; nj++) {
                float p = __expf(s[nj][r] - mn);
                s[nj][r] = p;
                rs += p;
            }
#pragma unroll
            for (int off = 1; off < 16; off <<= 1) rs += __shfl_xor(rs, off, 64);
            l_run[r] = l_run[r] * alpha[r] + rs;
        }
#pragma unroll
        for (int nj = 0; nj < 4; nj++)
#pragma unroll
            for (int r = 0; r < 4; r++)
                Ps[w][quad * 4 + r][nj * 16 + l16] = (__bf16)s[nj][r];
        bf16x8 pa0 = *(const bf16x8*)&Ps[w][l16][quad * 8];
        bf16x8 pa1 = *(const bf16x8*)&Ps[w][l16][32 + quad * 8];
#pragma unroll
        for (int dj = 0; dj < 4; dj++) {
#pragma unroll
            for (int r = 0; r < 4; r++) ctx[dj][r] *= alpha[r];
            const __bf16* vrow = Vtb + (size_t)(h * HD + dj * 16 + l16) * ldV + bl * LPN + kp0;
            bf16x8 bv0 = *(const bf16x8*)(vrow + quad * 8);
            bf16x8 bv1 = *(const bf16x8*)(vrow + 32 + quad * 8);
            ctx[dj] = __builtin_amdgcn_mfma_f32_16x16x32_bf16(pa0, bv0, ctx[dj], 0, 0, 0);
            ctx[dj] = __builtin_amdgcn_mfma_f32_16x16x32_bf16(pa1, bv1, ctx[dj], 0, 0, 0);
        }
    }
    const int base = ((bl * 4 + h) * 4 + sp) * 64;
#pragma unroll
    for (int dj = 0; dj < 4; dj++)
#pragma unroll
        for (int r = 0; r < 4; r++) {
            int q = w * 16 + quad * 4 + r;
            Op[(size_t)(base + q) * 64 + dj * 16 + l16] = (__bf16)(ctx[dj][r] / l_run[r]);
        }
    if (l16 == 0) {
#pragma unroll
        for (int r = 0; r < 4; r++) {
            int q = w * 16 + quad * 4 + r;
            Ml[(size_t)(base + q) * 2 + 0] = m_run[r];
            Ml[(size_t)(base + q) * 2 + 1] = l_run[r];
        }
    }
}

// combine 4 LP-split partials -> ctx bf16
__global__ __launch_bounds__(256) void combine_k(const __bf16* __restrict__ Op,
    const float* __restrict__ Ml, __bf16* __restrict__ O, int b0)
{
    const int bl = blockIdx.x >> 6, q = blockIdx.x & 63;
    const int t = threadIdx.x;
    const int h = t >> 6, d = t & 63;
    const int base = (bl * 4 + h) * 4;
    float ms[4], ls[4], m = -3e38f;
#pragma unroll
    for (int sp = 0; sp < 4; sp++) {
        ms[sp] = Ml[(size_t)((base + sp) * 64 + q) * 2 + 0];
        ls[sp] = Ml[(size_t)((base + sp) * 64 + q) * 2 + 1];
        m = fmaxf(m, ms[sp]);
    }
    float L = 0.f, o = 0.f;
#pragma unroll
    for (int sp = 0; sp < 4; sp++) {
        float wgt = __expf(ms[sp] - m) * ls[sp];
        L += wgt;
        o += wgt * (float)Op[(size_t)((base + sp) * 64 + q) * 64 + d];
    }
    O[((size_t)(b0 + bl) * 64 + q) * 256 + h * 64 + d] = (__bf16)(o / L);
}

// ---------------- LayerNorm(residual) ----------------
__device__ __forceinline__ float blockSum256(float v, float* red)
{
#pragma unroll
    for (int off = 32; off >= 1; off >>= 1) v += __shfl_down(v, off, 64);
    int wave = threadIdx.x >> 6, lane = threadIdx.x & 63;
    if (lane == 0) red[wave] = v;
    __syncthreads();
    float s = red[0] + red[1] + red[2] + red[3];
    __syncthreads();
    return s;
}

__global__ __launch_bounds__(256) void lnres_k(const float* __restrict__ A,
    const float* __restrict__ Bb, const float* __restrict__ g,
    const float* __restrict__ be, float* __restrict__ Y, __bf16* __restrict__ Yb)
{
    __shared__ float red[4];
    int r = blockIdx.x, t = threadIdx.x;
    float v = A[(size_t)r * 256 + t] + Bb[(size_t)r * 256 + t];
    float mean = blockSum256(v, red) * (1.f / 256.f);
    float d = v - mean;
    float var = blockSum256(d * d, red) * (1.f / 256.f);
    float o = d * rsqrtf(var + 1e-5f) * g[t] + be[t];
    Y[(size_t)r * 256 + t] = o;
    if (Yb) Yb[(size_t)r * 256 + t] = (__bf16)o;
}

// ---------------- fused head: mean-pool + fc1(relu) + fc2 ----------------
__global__ __launch_bounds__(256) void head_k(const float* __restrict__ Y,
    const float* __restrict__ fc1w, const float* __restrict__ fc1b,
    const float* __restrict__ fc2w, const float* __restrict__ fc2b,
    float* __restrict__ out)
{
    __shared__ float pooled[256];
    __shared__ float h[256];
    __shared__ float red[4];
    int b = blockIdx.x, t = threadIdx.x;
    float s = 0.f;
#pragma unroll 8
    for (int q = 0; q < 64; q++) s += Y[(size_t)(b * 64 + q) * 256 + t];
    pooled[t] = s / (64.f + 1e-6f);
    __syncthreads();
    float a = 0.f;
    for (int k = 0; k < 256; k += 4) {
        a += pooled[k + 0] * fc1w[(k + 0) * 256 + t];
        a += pooled[k + 1] * fc1w[(k + 1) * 256 + t];
        a += pooled[k + 2] * fc1w[(k + 2) * 256 + t];
        a += pooled[k + 3] * fc1w[(k + 3) * 256 + t];
    }
    h[t] = fmaxf(a + fc1b[t], 0.f);
    __syncthreads();
    float p = h[t] * fc2w[t];
    p = blockSum256(p, red);
    if (t == 0) out[b] = p + fc2b[0];
}

// ---------------- launch ----------------
extern "C" void kernel_launch(void* const* d_in, const int* in_sizes, int n_in,
                              void* d_out, int out_size, void* d_ws, size_t ws_size,
                              hipStream_t stream)
{
    const float* x     = (const float*)d_in[0];
    const int*   ei    = (const int*)d_in[1];
    const int*   pseq  = (const int*)d_in[3];
    const float* w1  = (const float*)d_in[4];
    const float* as1 = (const float*)d_in[5];
    const float* ad1 = (const float*)d_in[6];
    const float* b1  = (const float*)d_in[7];
    const float* w2  = (const float*)d_in[8];
    const float* as2 = (const float*)d_in[9];
    const float* ad2 = (const float*)d_in[10];
    const float* b2  = (const float*)d_in[11];
    const float* w3  = (const float*)d_in[12];
    const float* as3 = (const float*)d_in[13];
    const float* ad3 = (const float*)d_in[14];
    const float* b3  = (const float*)d_in[15];
    const float* emb    = (const float*)d_in[16];
    const float* conv_w = (const float*)d_in[17];
    const float* conv_b = (const float*)d_in[18];
    const float* wq = (const float*)d_in[19];
    const float* bq = (const float*)d_in[20];
    const float* wk = (const float*)d_in[21];
    const float* bk = (const float*)d_in[22];
    const float* wv = (const float*)d_in[23];
    const float* bv = (const float*)d_in[24];
    const float* wo = (const float*)d_in[25];
    const float* bo = (const float*)d_in[26];
    const float* ln1_g = (const float*)d_in[27];
    const float* ln1_b = (const float*)d_in[28];
    const float* ffw1  = (const float*)d_in[29];
    const float* ffb1  = (const float*)d_in[30];
    const float* ffw2  = (const float*)d_in[31];
    const float* ffb2  = (const float*)d_in[32];
    const float* ln2_g = (const float*)d_in[33];
    const float* ln2_b = (const float*)d_in[34];
    const float* fc1_w = (const float*)d_in[35];
    const float* fc1_b = (const float*)d_in[36];
    const float* fc2_w = (const float*)d_in[37];
    const float* fc2_b = (const float*)d_in[38];
    (void)in_sizes; (void)n_in; (void)out_size;

    char* ws = (char*)d_ws;
    size_t off = 0;
    auto alloc = [&](size_t bytes) -> char* {
        char* p = ws + off;
        off += (bytes + 255) & ~(size_t)255;
        return p;
    };
    // ---- fixed arena ----
    __bf16* hgb  = (__bf16*)alloc((size_t)NAT * 512 * 2);
    float* og    = (float*)alloc((size_t)NAT * 512 * 4);
    float* hb0   = (float*)alloc((size_t)NAT * 256 * 4);
    float* hb1   = (float*)alloc((size_t)NAT * 256 * 4);
    __bf16* xb   = (__bf16*)alloc((size_t)NAT * FIN * 2);
    __bf16* hbb  = (__bf16*)alloc((size_t)NAT * 256 * 2);
    __bf16* qbb  = (__bf16*)alloc((size_t)NAT * 256 * 2);
    __bf16* ctxbb= (__bf16*)alloc((size_t)NAT * 256 * 2);
    __bf16* ybb  = (__bf16*)alloc((size_t)NAT * 256 * 2);
    float* a_s   = (float*)alloc((size_t)NAT * 2 * 4);
    float* a_d   = (float*)alloc((size_t)NAT * 2 * 4);
    float* asd_p = (float*)alloc((size_t)16 * NAT * 4);
    int* deg     = (int*)alloc((size_t)NAT * 4);
    int* fill    = (int*)alloc((size_t)NAT * 4);
    int* rowptr  = (int*)alloc((size_t)(NAT + 1) * 4);
    int* csrc    = (int*)alloc((size_t)NED * 4);
    int* cdst    = (int*)alloc((size_t)NED * 4);
    float4* erec = (float4*)alloc((size_t)NED * 16);
    float* tap   = (float*)alloc((size_t)3 * 22 * 256 * 4);
    __bf16* w1T  = (__bf16*)alloc((size_t)512 * 64 * 2);
    __bf16* w2T  = (__bf16*)alloc((size_t)512 * 256 * 2);
    __bf16* w3T  = (__bf16*)alloc((size_t)512 * 256 * 2);
    __bf16* wkT  = (__bf16*)alloc((size_t)256 * 256 * 2);
    __bf16* wvT  = (__bf16*)alloc((size_t)256 * 256 * 2);
    __bf16* wqT  = (__bf16*)alloc((size_t)256 * 256 * 2);
    __bf16* woT  = (__bf16*)alloc((size_t)256 * 256 * 2);
    __bf16* f1T  = (__bf16*)alloc((size_t)1024 * 256 * 2);
    __bf16* f2T  = (__bf16*)alloc((size_t)256 * 1024 * 2);
    // ---- variable region ----
    size_t fixed_end = off;
    size_t rem = (ws_size > fixed_end) ? ws_size - fixed_end : 0;
    const size_t G1 = (size_t)LPN * 256 * 2;               // 0.5 MB: pconv/K/Vt per graph
    const size_t P1 = (size_t)4 * 4 * 64 * 64 * 2;         // 128 KB: bf16 partial O per graph
    const size_t M1 = (size_t)4 * 4 * 64 * 2 * 4;          // 8 KB: m,l per graph
    const size_t ffneed = (size_t)NAT * 1024 * 2 + (size_t)NAT * 256 * 4;
    int CB = 8;
    {
        const int cands[6] = {256, 128, 64, 32, 16, 8};
        for (int ci = 0; ci < 6; ci++) {
            size_t regneed = (size_t)cands[ci] * (3 * G1 + P1 + M1);
            if (regneed < ffneed) regneed = ffneed;
            if (regneed <= rem) { CB = cands[ci]; break; }
        }
    }
    char* region   = ws + fixed_end;
    __bf16* pconvb = (__bf16*)region;
    __bf16* kbb    = (__bf16*)(region + (size_t)CB * G1);
    __bf16* vtb    = (__bf16*)(region + 2 * (size_t)CB * G1);
    __bf16* opart  = (__bf16*)(region + 3 * (size_t)CB * G1);
    float*  mlpart = (float*)(region + (size_t)CB * (3 * G1 + P1));
    __bf16* ffbb   = (__bf16*)region;
    float*  y2     = (float*)(region + (size_t)NAT * 1024 * 2);
    float* attno = og;
    float* ybuf  = og + (size_t)NAT * 256;
    float* ff2o  = hb1;

    // ---------------- CSR build + conv tap table ----------------
    hipMemsetAsync(deg, 0, (size_t)NAT * 8, stream);   // deg + fill (adjacent)
    hipMemsetAsync(tap, 0, (size_t)3 * 22 * 256 * 4, stream);
    deg_k<<<NED / 256, 256, 0, stream>>>(ei, deg);
    scan_k<<<1, 256, 0, stream>>>(deg, rowptr);
    scat_k<<<NED / 256, 256, 0, stream>>>(ei, fill, rowptr, csrc, cdst);
    tap_k<<<264, 256, 0, stream>>>(emb, conv_w, tap);

    // ---------------- all conversions in one dispatch ----------------
    {
        Segs S;
        const float* srcs[10] = {x, w1, w2, w3, wk, wv, wq, wo, ffw1, ffw2};
        __bf16* dsts[10] = {xb, w1T, w2T, w3T, wkT, wvT, wqT, woT, f1T, f2T};
        int kd[10] = {0, 64, 256, 256, 256, 256, 256, 256, 256, 1024};
        int nd[10] = {0, 512, 512, 512, 256, 256, 256, 256, 1024, 256};
        int md[10] = {0, 1, 1, 1, 1, 1, 1, 1, 1, 1};
        int cnt[10] = {NAT * FIN, 32768, 131072, 131072,
                       65536, 65536, 65536, 65536, 262144, 262144};
        int run = 0;
        for (int i = 0; i < 10; i++) {
            S.src[i] = srcs[i]; S.dst[i] = dsts[i];
            S.kdim[i] = kd[i]; S.ndim[i] = nd[i]; S.mode[i] = md[i];
            S.start[i] = run; run += cnt[i];
        }
        S.start[10] = run; S.start[11] = run; S.start[12] = run;
        cvtall_k<<<(run + 255) / 256, 256, 0, stream>>>(S, run);
    }

    // ---------------- ligand GNN: 3 GAT layers ----------------
    const __bf16* WT[3] = {w1T, w2T, w3T};
    const float* asl[3] = {as1, as2, as3};
    const float* adl[3] = {ad1, ad2, ad3};
    const float* bl[3]  = {b1, b2, b3};
    float* houts[3] = {nullptr, nullptr, hb0};
    const __bf16* hinb = xb;
    int Kdim = FIN;
    for (int l = 0; l < 3; l++) {
        gemm_gat<<<dim3(4, NAT / 128), 512, 0, stream>>>(hinb, WT[l], asl[l], adl[l], hgb, asd_p, Kdim);
        fold_k<<<NAT / 256, 256, 0, stream>>>(asd_p, a_s, a_d);
        erec_k<<<NED / 256, 256, 0, stream>>>(csrc, cdst, a_s, a_d, erec);
        gat_agg<<<NAT / 4, 256, 0, stream>>>(rowptr, erec, hgb, a_s, a_d, bl[l], houts[l], hbb);
        hinb = hbb;
        Kdim = HID;
    }
    const float* lig = hb0;
    const __bf16* ligb = hbb;

    // ---------------- Q projection (scale 1/8 folded in) ----------------
    gemm_mfma<0, 1, 0><<<dim3(2, NAT / 128), 512, 0, stream>>>(ligb, wqT, bq, qbb, NAT, 256, 256, 0.125f);

    // ---------------- protein branch + attention, chunked over graphs ----------
    for (int b0 = 0; b0 < BGR; b0 += CB) {
        int Mc = CB * LPN;
        convg_k<<<Mc / 8, 256, 0, stream>>>(pseq, tap, conv_b, pconvb, b0);
        kv_mfma<<<dim3(4, Mc / 128), 512, 0, stream>>>(pconvb, wkT, wvT, bk, bv, kbb, vtb, Mc);
        attn3_k<<<CB * 16, 256, 0, stream>>>(qbb, kbb, vtb, pseq, opart, mlpart, b0, Mc);
        combine_k<<<CB * 64, 256, 0, stream>>>(opart, mlpart, ctxbb, b0);
    }

    // ---------------- attention out proj + LN + FFN + LN ----------------
    gemm_mfma<0, 0, 0><<<dim3(2, NAT / 128), 512, 0, stream>>>(ctxbb, woT, bo, attno, NAT, 256, 256, 1.f);
    lnres_k<<<NAT, 256, 0, stream>>>(lig, attno, ln1_g, ln1_b, ybuf, ybb);
    gemm_mfma<2, 1, 0><<<dim3(8, NAT / 128), 512, 0, stream>>>(ybb, f1T, ffb1, ffbb, NAT, 1024, 256, 1.f);
    gemm_mfma<0, 0, 0><<<dim3(2, NAT / 128), 512, 0, stream>>>(ffbb, f2T, ffb2, ff2o, NAT, 256, 1024, 1.f);
    lnres_k<<<NAT, 256, 0, stream>>>(ybuf, ff2o, ln2_g, ln2_b, y2, nullptr);

    // ---------------- fused head ----------------
    head_k<<<BGR, 256, 0, stream>>>(y2, fc1_w, fc1_b, fc2_w, fc2_b, (float*)d_out);
}